// Round 1
// baseline (1561.295 us; speedup 1.0000x reference)
//
#include <hip/hip_runtime.h>
#include <hip/hip_bf16.h>

// ---- problem constants ----
#define HH 12
#define DD 128
#define EE 1536
#define NBATCH 8
#define SEQ 3072
#define NBLK 256        // SEQ / CHK
#define CHK 12
#define CTXW 24
#define MTOK 24576      // NBATCH * SEQ

#define Q_SCALE_BASE 0.12751743f   // D^-0.5 / ln2
#define K_SCALE_F 1.8946361322f    // ln(1+e) / ln2

typedef short s16x8 __attribute__((ext_vector_type(8)));
typedef float f32x4 __attribute__((ext_vector_type(4)));

__device__ __forceinline__ float bf2f(unsigned short u) {
  return __builtin_bit_cast(float, ((unsigned int)u) << 16);
}
__device__ __forceinline__ unsigned short f2bf(float f) {
  unsigned int u = __builtin_bit_cast(unsigned int, f);
  u += 0x7fffu + ((u >> 16) & 1u);   // round-to-nearest-even
  return (unsigned short)(u >> 16);
}
__device__ __forceinline__ void bf2f2(unsigned int u, float& lo, float& hi) {
  lo = __builtin_bit_cast(float, u << 16);
  hi = __builtin_bit_cast(float, u & 0xffff0000u);
}

// async global->LDS, 16B per lane; lds dest must be wave-uniform base (lands at base + lane*16)
__device__ __forceinline__ void async16(const void* g, void* l) {
  __builtin_amdgcn_global_load_lds(
      (const __attribute__((address_space(1))) unsigned int*)g,
      (__attribute__((address_space(3))) unsigned int*)l, 16, 0, 0);
}

// ---- fp32 -> bf16 convert (vectorized) ----
__global__ __launch_bounds__(256) void k_cvt(const float4* __restrict__ in,
                                             ushort4* __restrict__ out, int n4) {
  int i = blockIdx.x * 256 + threadIdx.x;
  if (i < n4) {
    float4 v = in[i];
    ushort4 o;
    o.x = f2bf(v.x); o.y = f2bf(v.y); o.z = f2bf(v.z); o.w = f2bf(v.w);
    out[i] = o;
  }
}

// ---- per-dim query scale: Q_SCALE * softplus(per_dim_scale) ----
__global__ void k_qscale(const float* __restrict__ pds, float* __restrict__ qs) {
  int d = threadIdx.x;
  if (d < DD) {
    float x = pds[d];
    float sp = (x > 20.f) ? x : log1pf(expf(x));
    qs[d] = Q_SCALE_BASE * sp;
  }
}

// ---- rel_k = pos_emb @ w_rel.T  -> bf16 [CTXW][EE] ----
// grid: (12 col-blocks of 128, 2 p-halves), 256 threads
__global__ __launch_bounds__(256) void k_rel(const float* __restrict__ pos,
                                             const float* __restrict__ w_rel,
                                             unsigned short* __restrict__ rel16) {
  __shared__ unsigned short lp[12 * EE];
  const int t = threadIdx.x;
  const int p0 = blockIdx.y * 12;
  for (int i = t; i < 12 * EE / 4; i += 256) {
    float4 x = ((const float4*)(pos + (long)p0 * EE))[i];
    ushort4 o; o.x = f2bf(x.x); o.y = f2bf(x.y); o.z = f2bf(x.z); o.w = f2bf(x.w);
    ((ushort4*)lp)[i] = o;
  }
  __syncthreads();
  const int col = blockIdx.x * 128 + (t & 127);
  const int pg = t >> 7;  // 0 or 1 -> 6 p-rows each
  float acc[6] = {0.f, 0.f, 0.f, 0.f, 0.f, 0.f};
  const float* wr = w_rel + (long)col * EE;
  for (int e = 0; e < EE; ++e) {
    float w = wr[e];
#pragma unroll
    for (int i = 0; i < 6; ++i) acc[i] += w * bf2f(lp[(pg * 6 + i) * EE + e]);
  }
#pragma unroll
  for (int i = 0; i < 6; ++i)
    rel16[(long)(p0 + pg * 6 + i) * EE + col] = f2bf(acc[i]);
}

// ---- bf16 MFMA GEMM: C[M,N] = A[M,K] * Bt[N,K]^T ----
// 128x128 tile, BK=32, 256 threads = 4 waves in 2x2, 16x16x32 mfma, 4x4 tiles/wave.
// mode: 0 = none, 1 = per-dim qscale on col&127, 2 = scalar K_SCALE. c_f32: store fp32 else bf16.
__global__ __launch_bounds__(256) void k_gemm_bt(
    const unsigned short* __restrict__ A, const unsigned short* __restrict__ Bt,
    void* __restrict__ Cv, int M, int N, int K,
    int mode, const float* __restrict__ qscale, int c_f32) {
  __shared__ unsigned short lA[128 * 32];
  __shared__ unsigned short lB[128 * 32];

  const int tid = threadIdx.x;
  const int wave = tid >> 6;
  const int lane = tid & 63;
  const int quad = lane >> 4;
  const int l16 = lane & 15;
  const long bm = (long)blockIdx.x * 128;
  const long bn = (long)blockIdx.y * 128;
  const int wm = (wave & 1) * 64;
  const int wn = (wave >> 1) * 64;

  // staging: wave w loads tile rows [w*32, w*32+32) in two 16-row issues.
  // lane l -> row l>>2, 16B chunk l&3 ; LDS offset = lane*16 from wave-uniform base.
  const int srow = wave * 32 + (lane >> 2);
  const int skoff = (lane & 3) * 8;
  const unsigned short* gA0 = A + (bm + srow) * (long)K + skoff;
  const unsigned short* gB0 = Bt + (bn + srow) * (long)K + skoff;
  unsigned short* lA0 = &lA[(wave * 32) * 32];
  unsigned short* lA1 = &lA[(wave * 32 + 16) * 32];
  unsigned short* lB0 = &lB[(wave * 32) * 32];
  unsigned short* lB1 = &lB[(wave * 32 + 16) * 32];
  const long rstep = 16l * K;

  f32x4 acc[4][4] = {};

  for (int k0 = 0; k0 < K; k0 += 32) {
    __syncthreads();
    async16(gA0 + k0, lA0);
    async16(gA0 + k0 + rstep, lA1);
    async16(gB0 + k0, lB0);
    async16(gB0 + k0 + rstep, lB1);
    __syncthreads();   // drains vmcnt before barrier

    s16x8 af[4], bfr[4];
#pragma unroll
    for (int i = 0; i < 4; ++i)
      af[i] = *(const s16x8*)&lA[(wm + 16 * i + l16) * 32 + quad * 8];
#pragma unroll
    for (int j = 0; j < 4; ++j)
      bfr[j] = *(const s16x8*)&lB[(wn + 16 * j + l16) * 32 + quad * 8];
#pragma unroll
    for (int i = 0; i < 4; ++i)
#pragma unroll
      for (int j = 0; j < 4; ++j)
        acc[i][j] = __builtin_amdgcn_mfma_f32_16x16x32_bf16(af[i], bfr[j], acc[i][j], 0, 0, 0);
  }

  // epilogue: C/D layout col=lane&15, row=quad*4+reg
#pragma unroll
  for (int j = 0; j < 4; ++j) {
    const long col = bn + wn + 16 * j + l16;
    float scale = 1.0f;
    if (mode == 1) scale = qscale[col & (DD - 1)];
    else if (mode == 2) scale = K_SCALE_F;
#pragma unroll
    for (int i = 0; i < 4; ++i) {
      const long row0 = bm + wm + 16 * i + quad * 4;
#pragma unroll
      for (int r = 0; r < 4; ++r) {
        float vv = acc[i][j][r] * scale;
        if (c_f32) ((float*)Cv)[(row0 + r) * (long)N + col] = vv;
        else ((unsigned short*)Cv)[(row0 + r) * (long)N + col] = f2bf(vv);
      }
    }
  }
}

// ---- chunked local attention with Transformer-XL rel-shift ----
// grid (NBLK, NBATCH), 256 threads; loops over heads, stages per-head q/k/v/rel in LDS.
__global__ __launch_bounds__(256) void k_attn(
    const unsigned short* __restrict__ q, const unsigned short* __restrict__ k,
    const unsigned short* __restrict__ v, const unsigned short* __restrict__ rel,
    unsigned short* __restrict__ attn_out, float* __restrict__ aw_out) {
  const int n = blockIdx.x;
  const int b = blockIdx.y;
  const int t = threadIdx.x;

  __shared__ unsigned short lq[CHK][DD];
  __shared__ unsigned short lk[CTXW][DD];
  __shared__ unsigned short lv[CTXW][DD];
  __shared__ unsigned short lr[CTXW][DD];
  __shared__ float sac[CHK][CTXW];
  __shared__ float sbd[CHK][CTXW];
  __shared__ float sw[CHK][CTXW];

  const long tok0 = (long)b * SEQ + (long)n * CHK;

  for (int h = 0; h < HH; ++h) {
    const long hoff = (long)h * DD;
    if (t < 192) {  // 12 rows x 16 chunks of 16B
      int c = t >> 4, ch = t & 15;
      *(uint4*)&lq[c][ch * 8] = *(const uint4*)&q[(tok0 + c) * EE + hoff + ch * 8];
    }
    for (int u = t; u < 384; u += 256) {  // 24 rows x 16 chunks
      int j = u >> 4, ch = u & 15;
      int s = n * CHK + j - 12;  // left context PAST=12; right edge always in-range
      uint4 kv, vv;
      if (s >= 0) {
        long base = ((long)b * SEQ + s) * EE + hoff + ch * 8;
        kv = *(const uint4*)&k[base];
        vv = *(const uint4*)&v[base];
      } else {
        kv = make_uint4(0, 0, 0, 0);
        vv = make_uint4(0, 0, 0, 0);
      }
      *(uint4*)&lk[j][ch * 8] = kv;
      *(uint4*)&lv[j][ch * 8] = vv;
      *(uint4*)&lr[j][ch * 8] = *(const uint4*)&rel[(long)j * EE + hoff + ch * 8];
    }
    __syncthreads();

    // content (ac) and position (bd) scores: 288 (c,j) pairs
    for (int p = t; p < CHK * CTXW; p += 256) {
      int c = p / CTXW, j = p - c * CTXW;
      const unsigned int* uq = (const unsigned int*)&lq[c][0];
      const unsigned int* uk = (const unsigned int*)&lk[j][0];
      const unsigned int* ur = (const unsigned int*)&lr[j][0];
      float ac = 0.f, bd = 0.f;
#pragma unroll 8
      for (int d2 = 0; d2 < DD / 2; ++d2) {
        float a0, a1, k0f, k1f, r0, r1;
        bf2f2(uq[d2], a0, a1);
        bf2f2(uk[d2], k0f, k1f);
        bf2f2(ur[d2], r0, r1);
        ac += a0 * k0f + a1 * k1f;
        bd += a0 * r0 + a1 * r1;
      }
      sac[c][j] = ac;
      sbd[c][j] = bd;
    }
    __syncthreads();

    // rel-shift + softcap + softmax; one thread per query row
    if (t < CHK) {
      const int c = t;
      float lg[CTXW];
      float mx = -3.0e38f;
#pragma unroll
      for (int j = 0; j < CTXW; ++j) {
        float y;
        if (j >= c) y = sbd[c][j - c];
        else if (j == c - 1) y = 0.f;                       // pad column of rel-shift
        else y = sbd[c - 1][j - c + CTXW + 1];              // wrap rows of rel-shift
        float x = sac[c][j] + y;
        x = 50.f * tanhf(x * 0.02f);                        // logit softcap
        lg[j] = x;
        mx = fmaxf(mx, x);
      }
      float ssum = 0.f;
#pragma unroll
      for (int j = 0; j < CTXW; ++j) {
        float e = expf(lg[j] - mx);
        lg[j] = e;
        ssum += e;
      }
      float inv = 1.f / ssum;
      float* awp = aw_out + ((((long)b * HH + h) * NBLK + n) * CHK + c) * CTXW;
#pragma unroll
      for (int j = 0; j < CTXW; ++j) {
        float wj = lg[j] * inv;
        sw[c][j] = wj;
        awp[j] = wj;  // attn_weights output (fp32)
      }
    }
    __syncthreads();

    // out[c][d] = sum_j w[c][j] * v[j][d]
    for (int p = t; p < CHK * DD; p += 256) {
      int c = p >> 7, d = p & (DD - 1);
      float accv = 0.f;
#pragma unroll
      for (int j = 0; j < CTXW; ++j) accv += sw[c][j] * bf2f(lv[j][d]);
      attn_out[(tok0 + c) * EE + hoff + d] = f2bf(accv);
    }
    __syncthreads();
  }
}

extern "C" void kernel_launch(void* const* d_in, const int* in_sizes, int n_in,
                              void* d_out, int out_size, void* d_ws, size_t ws_size,
                              hipStream_t stream) {
  const float* hs     = (const float*)d_in[0];
  const float* pos    = (const float*)d_in[1];
  const float* w_q    = (const float*)d_in[2];
  const float* w_k    = (const float*)d_in[3];
  const float* w_v    = (const float*)d_in[4];
  const float* w_post = (const float*)d_in[5];
  const float* w_rel  = (const float*)d_in[6];
  const float* pds    = (const float*)d_in[7];

  char* ws = (char*)d_ws;
  const size_t TOKB = (size_t)MTOK * EE * 2;        // 75,497,472 bytes per [MTOK,EE] bf16
  const size_t WB   = (size_t)EE * EE * 2;          // 4,718,592 per weight
  unsigned short* hs16   = (unsigned short*)(ws);
  unsigned short* q16    = (unsigned short*)(ws + TOKB);
  unsigned short* k16    = (unsigned short*)(ws + 2 * TOKB);
  unsigned short* v16    = (unsigned short*)(ws + 3 * TOKB);
  unsigned short* wq16   = (unsigned short*)(ws + 4 * TOKB);
  unsigned short* wk16   = (unsigned short*)(ws + 4 * TOKB + WB);
  unsigned short* wv16   = (unsigned short*)(ws + 4 * TOKB + 2 * WB);
  unsigned short* wp16   = (unsigned short*)(ws + 4 * TOKB + 3 * WB);
  unsigned short* rel16  = (unsigned short*)(ws + 4 * TOKB + 4 * WB);
  float* qscale          = (float*)(ws + 4 * TOKB + 4 * WB + CTXW * EE * 2);
  unsigned short* attn16 = hs16;  // hs16 dead after the three projection GEMMs

  float* out = (float*)d_out;
  float* aw  = out + (size_t)MTOK * EE;

  // bf16 conversions
  k_cvt<<<36864, 256, 0, stream>>>((const float4*)hs, (ushort4*)hs16, MTOK * EE / 4);
  k_cvt<<<2304, 256, 0, stream>>>((const float4*)w_q, (ushort4*)wq16, EE * EE / 4);
  k_cvt<<<2304, 256, 0, stream>>>((const float4*)w_k, (ushort4*)wk16, EE * EE / 4);
  k_cvt<<<2304, 256, 0, stream>>>((const float4*)w_v, (ushort4*)wv16, EE * EE / 4);
  k_cvt<<<2304, 256, 0, stream>>>((const float4*)w_post, (ushort4*)wp16, EE * EE / 4);
  k_qscale<<<1, 128, 0, stream>>>(pds, qscale);
  k_rel<<<dim3(12, 2), 256, 0, stream>>>(pos, w_rel, rel16);

  // projections (scales fused in epilogue)
  k_gemm_bt<<<dim3(192, 12), 256, 0, stream>>>(hs16, wq16, q16, MTOK, EE, EE, 1, qscale, 0);
  k_gemm_bt<<<dim3(192, 12), 256, 0, stream>>>(hs16, wk16, k16, MTOK, EE, EE, 2, nullptr, 0);
  k_gemm_bt<<<dim3(192, 12), 256, 0, stream>>>(hs16, wv16, v16, MTOK, EE, EE, 0, nullptr, 0);

  // attention (writes attn_weights fp32 + context bf16)
  k_attn<<<dim3(NBLK, NBATCH), 256, 0, stream>>>(q16, k16, v16, rel16, attn16, aw);

  // output projection -> fp32 d_out
  k_gemm_bt<<<dim3(192, 12), 256, 0, stream>>>(attn16, wp16, out, MTOK, EE, EE, 0, nullptr, 1);
}

// Round 2
// 1260.965 us; speedup vs baseline: 1.2382x; 1.2382x over previous
//
#include <hip/hip_runtime.h>
#include <hip/hip_bf16.h>

// ---- problem constants ----
#define HH 12
#define DD 128
#define EE 1536
#define QKVP 4608       // fused q|k|v row pitch (shorts)
#define NBATCH 8
#define SEQ 3072
#define NBLK 256        // SEQ / CHK
#define CHK 12
#define CTXW 24
#define MTOK 24576      // NBATCH * SEQ

#define Q_SCALE_BASE 0.12751743f   // D^-0.5 / ln2
#define K_SCALE_F 1.8946361322f    // ln(1+e) / ln2

#define PITCH 65        // LDS row pitch in 4B words (odd -> bank stride 1, conflict-free)

typedef short s16x8 __attribute__((ext_vector_type(8)));
typedef float f32x4 __attribute__((ext_vector_type(4)));

__device__ __forceinline__ float bf2f(unsigned short u) {
  return __builtin_bit_cast(float, ((unsigned int)u) << 16);
}
__device__ __forceinline__ unsigned short f2bf(float f) {
  unsigned int u = __builtin_bit_cast(unsigned int, f);
  u += 0x7fffu + ((u >> 16) & 1u);   // round-to-nearest-even
  return (unsigned short)(u >> 16);
}
__device__ __forceinline__ void bf2f2(unsigned int u, float& lo, float& hi) {
  lo = __builtin_bit_cast(float, u << 16);
  hi = __builtin_bit_cast(float, u & 0xffff0000u);
}

// async global->LDS, 16B per lane; lds dest must be wave-uniform base (lands at base + lane*16)
__device__ __forceinline__ void async16(const void* g, void* l) {
  __builtin_amdgcn_global_load_lds(
      (const __attribute__((address_space(1))) unsigned int*)g,
      (__attribute__((address_space(3))) unsigned int*)l, 16, 0, 0);
}

// ---- fp32 -> bf16 convert (vectorized) ----
__global__ __launch_bounds__(256) void k_cvt(const float4* __restrict__ in,
                                             ushort4* __restrict__ out, int n4) {
  int i = blockIdx.x * 256 + threadIdx.x;
  if (i < n4) {
    float4 v = in[i];
    ushort4 o;
    o.x = f2bf(v.x); o.y = f2bf(v.y); o.z = f2bf(v.z); o.w = f2bf(v.w);
    out[i] = o;
  }
}

// ---- per-dim query scale: Q_SCALE * softplus(per_dim_scale) ----
__global__ void k_qscale(const float* __restrict__ pds, float* __restrict__ qs) {
  int d = threadIdx.x;
  if (d < DD) {
    float x = pds[d];
    float sp = (x > 20.f) ? x : log1pf(expf(x));
    qs[d] = Q_SCALE_BASE * sp;
  }
}

// ---- rel_k = pos_emb @ w_rel.T  -> bf16 [CTXW][EE] ----
__global__ __launch_bounds__(256) void k_rel(const float* __restrict__ pos,
                                             const float* __restrict__ w_rel,
                                             unsigned short* __restrict__ rel16) {
  __shared__ unsigned short lp[12 * EE];
  const int t = threadIdx.x;
  const int p0 = blockIdx.y * 12;
  for (int i = t; i < 12 * EE / 4; i += 256) {
    float4 x = ((const float4*)(pos + (long)p0 * EE))[i];
    ushort4 o; o.x = f2bf(x.x); o.y = f2bf(x.y); o.z = f2bf(x.z); o.w = f2bf(x.w);
    ((ushort4*)lp)[i] = o;
  }
  __syncthreads();
  const int col = blockIdx.x * 128 + (t & 127);
  const int pg = t >> 7;  // 0 or 1 -> 6 p-rows each
  float acc[6] = {0.f, 0.f, 0.f, 0.f, 0.f, 0.f};
  const float* wr = w_rel + (long)col * EE;
  for (int e = 0; e < EE; ++e) {
    float w = wr[e];
#pragma unroll
    for (int i = 0; i < 6; ++i) acc[i] += w * bf2f(lp[(pg * 6 + i) * EE + e]);
  }
#pragma unroll
  for (int i = 0; i < 6; ++i)
    rel16[(long)(p0 + pg * 6 + i) * EE + col] = f2bf(acc[i]);
}

// ---- bf16 MFMA GEMM: C[M,N] = A[M,K] * Bt[N,K]^T ----
// 128x128 tile, BK=32, 256 threads = 4 waves in 2x2, 16x16x32 mfma, 4x4 tiles/wave.
// mode: 0 = none, 3 = fused qkv col-scale. c_f32: store fp32 else bf16.
__global__ __launch_bounds__(256) void k_gemm_bt(
    const unsigned short* __restrict__ A, const unsigned short* __restrict__ Bt,
    void* __restrict__ Cv, int M, int N, int K,
    int mode, const float* __restrict__ qscale, int c_f32) {
  __shared__ unsigned short lA[128 * 32];
  __shared__ unsigned short lB[128 * 32];

  const int tid = threadIdx.x;
  const int wave = tid >> 6;
  const int lane = tid & 63;
  const int quad = lane >> 4;
  const int l16 = lane & 15;
  const long bm = (long)blockIdx.x * 128;
  const long bn = (long)blockIdx.y * 128;
  const int wm = (wave & 1) * 64;
  const int wn = (wave >> 1) * 64;

  const int srow = wave * 32 + (lane >> 2);
  const int skoff = (lane & 3) * 8;
  const unsigned short* gA0 = A + (bm + srow) * (long)K + skoff;
  const unsigned short* gB0 = Bt + (bn + srow) * (long)K + skoff;
  unsigned short* lA0 = &lA[(wave * 32) * 32];
  unsigned short* lA1 = &lA[(wave * 32 + 16) * 32];
  unsigned short* lB0 = &lB[(wave * 32) * 32];
  unsigned short* lB1 = &lB[(wave * 32 + 16) * 32];
  const long rstep = 16l * K;

  f32x4 acc[4][4] = {};

  for (int k0 = 0; k0 < K; k0 += 32) {
    __syncthreads();
    async16(gA0 + k0, lA0);
    async16(gA0 + k0 + rstep, lA1);
    async16(gB0 + k0, lB0);
    async16(gB0 + k0 + rstep, lB1);
    __syncthreads();

    s16x8 af[4], bfr[4];
#pragma unroll
    for (int i = 0; i < 4; ++i)
      af[i] = *(const s16x8*)&lA[(wm + 16 * i + l16) * 32 + quad * 8];
#pragma unroll
    for (int j = 0; j < 4; ++j)
      bfr[j] = *(const s16x8*)&lB[(wn + 16 * j + l16) * 32 + quad * 8];
#pragma unroll
    for (int i = 0; i < 4; ++i)
#pragma unroll
      for (int j = 0; j < 4; ++j)
        acc[i][j] = __builtin_amdgcn_mfma_f32_16x16x32_bf16(af[i], bfr[j], acc[i][j], 0, 0, 0);
  }

  // epilogue: C/D layout col=lane&15, row=quad*4+reg
#pragma unroll
  for (int j = 0; j < 4; ++j) {
    const long col = bn + wn + 16 * j + l16;
    float scale = 1.0f;
    if (mode == 3)
      scale = (col < 1536) ? qscale[col & (DD - 1)] : (col < 3072 ? K_SCALE_F : 1.0f);
#pragma unroll
    for (int i = 0; i < 4; ++i) {
      const long row0 = bm + wm + 16 * i + quad * 4;
#pragma unroll
      for (int r = 0; r < 4; ++r) {
        float vv = acc[i][j][r] * scale;
        if (c_f32) ((float*)Cv)[(row0 + r) * (long)N + col] = vv;
        else ((unsigned short*)Cv)[(row0 + r) * (long)N + col] = f2bf(vv);
      }
    }
  }
}

// ---- chunked local attention, one block per (b, n, h) ----
// LDS pitch 65 words -> conflict-free score/output phases.
__global__ __launch_bounds__(256) void k_attn(
    const unsigned short* __restrict__ qkv, const unsigned short* __restrict__ rel,
    unsigned short* __restrict__ attn_out, float* __restrict__ aw_out) {
  const int n = blockIdx.x;
  const int b = blockIdx.y;
  const int h = blockIdx.z;
  const int t = threadIdx.x;

  __shared__ unsigned int lq[CHK * PITCH];
  __shared__ unsigned int lk[CTXW * PITCH];
  __shared__ unsigned int lv[CTXW * PITCH];
  __shared__ unsigned int lr[CTXW * PITCH];
  __shared__ float sac[CHK * CTXW];
  __shared__ float sbd[CHK * CTXW];
  __shared__ float smax[CHK];
  __shared__ float sinv[CHK];

  const long tok0 = (long)b * SEQ + (long)n * CHK;
  const long hq = (long)h * DD;

  // ---- stage q: 12 rows x 16 uint4 ----
  for (int u = t; u < CHK * 16; u += 256) {
    int r = u >> 4, w4 = u & 15;
    uint4 x = *(const uint4*)&qkv[(tok0 + r) * QKVP + hq + w4 * 8];
    unsigned int* d = &lq[r * PITCH + w4 * 4];
    d[0] = x.x; d[1] = x.y; d[2] = x.z; d[3] = x.w;
  }
  // ---- stage k, v (with left halo), rel: 24 rows x 16 uint4 each ----
  for (int u = t; u < CTXW * 16; u += 256) {
    int r = u >> 4, w4 = u & 15;
    int s = n * CHK + r - 12;
    uint4 kx, vx;
    if (s >= 0) {
      const unsigned short* base = &qkv[((long)b * SEQ + s) * QKVP + hq];
      kx = *(const uint4*)&base[1536 + w4 * 8];
      vx = *(const uint4*)&base[3072 + w4 * 8];
    } else {
      kx = make_uint4(0, 0, 0, 0);
      vx = make_uint4(0, 0, 0, 0);
    }
    uint4 rx = *(const uint4*)&rel[(long)r * EE + hq + w4 * 8];
    unsigned int* dk = &lk[r * PITCH + w4 * 4];
    unsigned int* dv = &lv[r * PITCH + w4 * 4];
    unsigned int* dr = &lr[r * PITCH + w4 * 4];
    dk[0] = kx.x; dk[1] = kx.y; dk[2] = kx.z; dk[3] = kx.w;
    dv[0] = vx.x; dv[1] = vx.y; dv[2] = vx.z; dv[3] = vx.w;
    dr[0] = rx.x; dr[1] = rx.y; dr[2] = rx.z; dr[3] = rx.w;
  }
  __syncthreads();

  // ---- scores: 288 (c,j) pairs, dot over 64 dwords (conflict-free banks) ----
  for (int p = t; p < CHK * CTXW; p += 256) {
    int c = p / CTXW, j = p - c * CTXW;
    const unsigned int* uq = &lq[c * PITCH];
    const unsigned int* uk = &lk[j * PITCH];
    const unsigned int* ur = &lr[j * PITCH];
    float ac = 0.f, bd = 0.f;
#pragma unroll 16
    for (int d2 = 0; d2 < DD / 2; ++d2) {
      float a0, a1, k0f, k1f, r0, r1;
      bf2f2(uq[d2], a0, a1);
      bf2f2(uk[d2], k0f, k1f);
      bf2f2(ur[d2], r0, r1);
      ac += a0 * k0f + a1 * k1f;
      bd += a0 * r0 + a1 * r1;
    }
    sac[p] = ac;
    sbd[p] = bd;
  }
  __syncthreads();

  // ---- rel-shift + softcap (parallel over 288) ----
  for (int p = t; p < CHK * CTXW; p += 256) {
    int c = p / CTXW, j = p - c * CTXW;
    float y;
    if (j >= c) y = sbd[c * CTXW + (j - c)];
    else if (j == c - 1) y = 0.f;
    else y = sbd[(c - 1) * CTXW + (j - c + CTXW + 1)];
    float x = (sac[p] + y) * 0.02f;
    x = fminf(fmaxf(x, -15.f), 15.f);
    float e2 = __expf(2.f * x);
    sac[p] = 50.f * (e2 - 1.f) / (e2 + 1.f);   // 50*tanh(x)
  }
  __syncthreads();

  // ---- row max ----
  if (t < CHK) {
    float m = -3.0e38f;
#pragma unroll
    for (int j = 0; j < CTXW; ++j) m = fmaxf(m, sac[t * CTXW + j]);
    smax[t] = m;
  }
  __syncthreads();

  // ---- exp (parallel) ----
  for (int p = t; p < CHK * CTXW; p += 256) {
    int c = p / CTXW;
    sbd[p] = __expf(sac[p] - smax[c]);
  }
  __syncthreads();

  // ---- row sum ----
  if (t < CHK) {
    float s = 0.f;
#pragma unroll
    for (int j = 0; j < CTXW; ++j) s += sbd[t * CTXW + j];
    sinv[t] = 1.f / s;
  }
  __syncthreads();

  // ---- normalize + write attn_weights ----
  for (int p = t; p < CHK * CTXW; p += 256) {
    int c = p / CTXW, j = p - c * CTXW;
    float w = sbd[p] * sinv[c];
    sac[p] = w;
    aw_out[((((long)b * HH + h) * NBLK + n) * CHK + c) * CTXW + j] = w;
  }
  __syncthreads();

  // ---- output: O[c][d] = sum_j w[c][j] * v[j][d], dword-paired d ----
  for (int p = t; p < CHK * (DD / 2); p += 256) {
    int c = p >> 6, d2 = p & 63;
    float a0 = 0.f, a1 = 0.f;
#pragma unroll
    for (int j = 0; j < CTXW; ++j) {
      float w = sac[c * CTXW + j];
      float v0, v1;
      bf2f2(lv[j * PITCH + d2], v0, v1);
      a0 += w * v0; a1 += w * v1;
    }
    unsigned int packed = ((unsigned int)f2bf(a1) << 16) | (unsigned int)f2bf(a0);
    *(unsigned int*)&attn_out[(tok0 + c) * EE + hq + d2 * 2] = packed;
  }
}

extern "C" void kernel_launch(void* const* d_in, const int* in_sizes, int n_in,
                              void* d_out, int out_size, void* d_ws, size_t ws_size,
                              hipStream_t stream) {
  const float* hs     = (const float*)d_in[0];
  const float* pos    = (const float*)d_in[1];
  const float* w_q    = (const float*)d_in[2];
  const float* w_k    = (const float*)d_in[3];
  const float* w_v    = (const float*)d_in[4];
  const float* w_post = (const float*)d_in[5];
  const float* w_rel  = (const float*)d_in[6];
  const float* pds    = (const float*)d_in[7];

  char* ws = (char*)d_ws;
  const size_t TOKB = (size_t)MTOK * EE * 2;        // bytes per [MTOK,EE] bf16
  const size_t WB   = (size_t)EE * EE * 2;
  unsigned short* hs16   = (unsigned short*)(ws);
  unsigned short* qkv16  = (unsigned short*)(ws + TOKB);           // [MTOK][4608]
  unsigned short* wq16   = (unsigned short*)(ws + 4 * TOKB);       // wq|wk|wv contiguous
  unsigned short* wk16   = (unsigned short*)(ws + 4 * TOKB + WB);
  unsigned short* wv16   = (unsigned short*)(ws + 4 * TOKB + 2 * WB);
  unsigned short* wp16   = (unsigned short*)(ws + 4 * TOKB + 3 * WB);
  unsigned short* rel16  = (unsigned short*)(ws + 4 * TOKB + 4 * WB);
  float* qscale          = (float*)(ws + 4 * TOKB + 4 * WB + CTXW * EE * 2);
  unsigned short* attn16 = hs16;  // hs16 dead after qkv GEMM

  float* out = (float*)d_out;
  float* aw  = out + (size_t)MTOK * EE;

  // bf16 conversions
  k_cvt<<<36864, 256, 0, stream>>>((const float4*)hs, (ushort4*)hs16, MTOK * EE / 4);
  k_cvt<<<2304, 256, 0, stream>>>((const float4*)w_q, (ushort4*)wq16, EE * EE / 4);
  k_cvt<<<2304, 256, 0, stream>>>((const float4*)w_k, (ushort4*)wk16, EE * EE / 4);
  k_cvt<<<2304, 256, 0, stream>>>((const float4*)w_v, (ushort4*)wv16, EE * EE / 4);
  k_cvt<<<2304, 256, 0, stream>>>((const float4*)w_post, (ushort4*)wp16, EE * EE / 4);
  k_qscale<<<1, 128, 0, stream>>>(pds, qscale);
  k_rel<<<dim3(12, 2), 256, 0, stream>>>(pos, w_rel, rel16);

  // fused q|k|v projection: Bt = [wq;wk;wv] (contiguous), N=4608, scales in epilogue
  k_gemm_bt<<<dim3(192, 36), 256, 0, stream>>>(hs16, wq16, qkv16, MTOK, QKVP, EE, 3, qscale, 0);

  // attention: one block per (b, n, h)
  k_attn<<<dim3(NBLK, NBATCH, HH), 256, 0, stream>>>(qkv16, rel16, attn16, aw);

  // output projection -> fp32 d_out
  k_gemm_bt<<<dim3(192, 12), 256, 0, stream>>>(attn16, wp16, out, MTOK, EE, EE, 0, nullptr, 1);
}